// Round 15
// baseline (189.461 us; speedup 1.0000x reference)
//
#include <hip/hip_runtime.h>

// MFMA fragment types (f16)
typedef _Float16 f16x8 __attribute__((ext_vector_type(8)));
typedef __fp16   fp16x2 __attribute__((ext_vector_type(2)));
typedef float f32x16 __attribute__((ext_vector_type(16)));

__device__ __forceinline__ unsigned pkrtz(float a, float b) {
    fp16x2 h = __builtin_amdgcn_cvt_pkrtz(a, b);   // src0->low, src1->high
    union { fp16x2 h; unsigned u; } c; c.h = h; return c.u;
}

__device__ __forceinline__ unsigned short f2h(float f) {
    _Float16 h = (_Float16)f;
    union { _Float16 h; unsigned short s; } c; c.h = h; return c.s;
}

// sigmoid((q·k)/8) with -0.125*log2e pre-folded into Q: s = 1/(1+2^t)
__device__ __forceinline__ float sig_from_t(float t) {
    return __builtin_amdgcn_rcpf(1.0f + __builtin_exp2f(t));
}

// ---------------------------------------------------------------------------
// prep (height stage), SPLIT over z: z=0 -> Q, z=1 -> V. Per (b,bx=w) block:
// slab[k=h][c] = feature[b,h,w,c]; GEMM vs one weight matrix (half the chain
// of the fused version; 2 blocks/CU instead of 1).
//   Q -> Qg [b][4096][64] f16 row-major ; V -> Vtg [b][64][4096] f16 (T)
// ---------------------------------------------------------------------------
__global__ __launch_bounds__(256) void prep_kernel(
    const float* __restrict__ src,
    const float* __restrict__ wq, const float* __restrict__ bq,
    const float* __restrict__ wv, const float* __restrict__ bv,
    unsigned short* __restrict__ Qg, unsigned short* __restrict__ Vtg)
{
    __shared__ float slab[64][65];
    __shared__ float wsh[4096];

    const int t  = threadIdx.x;
    const int bx = blockIdx.x, b = blockIdx.y, sel = blockIdx.z;
    const float* wsel = sel ? wv : wq;
    const float* bsel = sel ? bv : bq;

    {   // stage the one weight matrix this block needs
        const float4* w4 = (const float4*)wsel;
        float4* s4 = (float4*)wsh;
        #pragma unroll
        for (int i = 0; i < 4; ++i) s4[i*256 + t] = w4[i*256 + t];
    }
    {   // stage slab: k=h rows (stride 4096), bx=w fixed
        const int k = t >> 2, c0 = (t & 3) << 4;
        const size_t sb = (size_t)b*262144 + (size_t)k*4096 + (size_t)bx*64 + c0;
        #pragma unroll
        for (int i = 0; i < 4; ++i)
            *(float4*)&slab[k][c0 + i*4] = *(const float4*)&src[sb + i*4];
    }
    __syncthreads();

    const int c = t & 63, jg = t >> 6;
    float acc[16];
    #pragma unroll
    for (int jj = 0; jj < 16; ++jj) acc[jj] = bsel[jg*16 + jj];
    for (int k = 0; k < 64; ++k) {
        const float xv = slab[k][c];
        const float* wr = &wsh[k*64 + jg*16];
        #pragma unroll
        for (int jj = 0; jj < 16; ++jj) acc[jj] += xv * wr[jj];
    }
    const int token = bx*64 + c;
    if (sel == 0) {
        union { unsigned u[8]; uint4 v[2]; } qp;
        #pragma unroll
        for (int jj = 0; jj < 8; ++jj) qp.u[jj] = pkrtz(acc[2*jj], acc[2*jj+1]);
        const size_t qoff = ((size_t)b*4096 + token)*64 + jg*16;
        *(uint4*)&Qg[qoff]     = qp.v[0];
        *(uint4*)&Qg[qoff + 8] = qp.v[1];
    } else {
        #pragma unroll
        for (int jj = 0; jj < 16; ++jj)
            Vtg[((size_t)b*64 + jg*16 + jj)*4096 + token] = f2h(acc[jj]);
    }
}

// ---------------------------------------------------------------------------
// prep_w (width stage), SPLIT over z like prep, FUSED with fold_h:
// slab = feature + g*sum_ks(P_h) (both z-blocks compute the fold; only z=0
// writes x1 for final_kernel).
// ---------------------------------------------------------------------------
__global__ __launch_bounds__(256) void prep_w_kernel(
    const float* __restrict__ feature, const float* __restrict__ Pin,
    const float* __restrict__ gate,
    const float* __restrict__ wq, const float* __restrict__ bq,
    const float* __restrict__ wv, const float* __restrict__ bv,
    unsigned short* __restrict__ Qg, unsigned short* __restrict__ Vtg,
    float* __restrict__ x1out, int nsplit)
{
    __shared__ float slab[64][65];
    __shared__ float wsh[4096];

    const int t  = threadIdx.x;
    const int bx = blockIdx.x, b = blockIdx.y, sel = blockIdx.z;   // bx = h
    const float* wsel = sel ? wv : wq;
    const float* bsel = sel ? bv : bq;

    {   // stage the one weight matrix
        const float4* w4 = (const float4*)wsel;
        float4* s4 = (float4*)wsh;
        #pragma unroll
        for (int i = 0; i < 4; ++i) s4[i*256 + t] = w4[i*256 + t];
    }
    {   // stage slab with inline fold: P_h[ks][b][d=h][token=w*64+c]
        const int k = t >> 2, c0 = (t & 3) << 4;
        const size_t off = (size_t)bx*4096 + (size_t)k*64 + c0;  // h*4096 + w*64 + c
        const size_t fb  = (size_t)b*262144 + off;
        const float g = gate[0];
        #pragma unroll
        for (int i = 0; i < 4; ++i) {
            float4 v  = *(const float4*)&feature[fb + i*4];
            float sx = 0.f, sy = 0.f, sz = 0.f, sw = 0.f;
            for (int ks = 0; ks < nsplit; ++ks) {
                float4 pk = *(const float4*)&Pin[((size_t)(ks*4 + b) << 18) + off + i*4];
                sx += pk.x; sy += pk.y; sz += pk.z; sw += pk.w;
            }
            v.x += g * sx; v.y += g * sy; v.z += g * sz; v.w += g * sw;
            *(float4*)&slab[k][c0 + i*4] = v;
            if (sel == 0) *(float4*)&x1out[fb + i*4] = v;
        }
    }
    __syncthreads();

    const int c = t & 63, jg = t >> 6;
    float acc[16];
    #pragma unroll
    for (int jj = 0; jj < 16; ++jj) acc[jj] = bsel[jg*16 + jj];
    for (int k = 0; k < 64; ++k) {
        const float xv = slab[k][c];
        const float* wr = &wsh[k*64 + jg*16];
        #pragma unroll
        for (int jj = 0; jj < 16; ++jj) acc[jj] += xv * wr[jj];
    }
    const int token = bx*64 + c;
    if (sel == 0) {
        union { unsigned u[8]; uint4 v[2]; } qp;
        #pragma unroll
        for (int jj = 0; jj < 8; ++jj) qp.u[jj] = pkrtz(acc[2*jj], acc[2*jj+1]);
        const size_t qoff = ((size_t)b*4096 + token)*64 + jg*16;
        *(uint4*)&Qg[qoff]     = qp.v[0];
        *(uint4*)&Qg[qoff + 8] = qp.v[1];
    } else {
        #pragma unroll
        for (int jj = 0; jj < 16; ++jj)
            Vtg[((size_t)b*64 + jg*16 + jj)*4096 + token] = f2h(acc[jj]);
    }
}

// ---------------------------------------------------------------------------
// attn — EXACT r11 core (measured 45.2 us; r13/r14 variants were slower).
// f16 MFMA 32x32x16; scale folded into Q frags; S transpose in registers via
// __shfl_xor(·,32); single-buffer K/V staging, reg prefetch, 2 barriers/iter;
// partial stores P[ksplit][b][d][token].
// ---------------------------------------------------------------------------
__global__ __launch_bounds__(256) void attn_kernel(
    const unsigned short* __restrict__ Qg,
    const unsigned short* __restrict__ Vtg,
    float* __restrict__ P)
{
    __shared__ unsigned short Ksh[64][72];
    __shared__ unsigned short Vts[64][72];

    const int t = threadIdx.x;
    const int mb = blockIdx.x, b = blockIdx.y, ksplit = blockIdx.z;
    const int nsp = gridDim.z;
    const int niter = 64 / nsp;
    const int keybase = ksplit * (4096 / nsp);
    const int lane = t & 63, w = t >> 6;
    const int l32 = lane & 31, hi = lane >> 5;

    const unsigned short* Qbase = Qg  + (size_t)b*262144;
    const unsigned short* Vbase = Vtg + (size_t)b*262144;

    // Q B-frags (n=query=l32, k=d=s*16+hi*8+j), scaled by -0.125*log2(e)
    f16x8 qb[4];
    {
        const unsigned short* qrow = Qbase + (size_t)(mb*128 + w*32 + l32)*64 + hi*8;
        const _Float16 sc = (_Float16)(-0.180336880f);
        #pragma unroll
        for (int s = 0; s < 4; ++s) {
            f16x8 q = *(const f16x8*)(qrow + s*16);
            qb[s] = q * sc;
        }
    }

    f32x16 y[2];
    #pragma unroll
    for (int i = 0; i < 16; ++i) { y[0][i] = 0.f; y[1][i] = 0.f; }

    const int lrow = t >> 2;
    const int loff = (t & 3) << 4;
    {   // prologue: stage tile 0
        const uint4* gk = (const uint4*)(Qbase + (size_t)(keybase + lrow)*64 + loff);
        uint4 k0 = gk[0], k1 = gk[1];
        const uint4* gv = (const uint4*)(Vbase + (size_t)lrow*4096 + keybase + loff);
        uint4 v0 = gv[0], v1 = gv[1];
        *(uint4*)&Ksh[lrow][loff]     = k0;
        *(uint4*)&Ksh[lrow][loff + 8] = k1;
        *(uint4*)&Vts[lrow][loff]     = v0;
        *(uint4*)&Vts[lrow][loff + 8] = v1;
    }
    __syncthreads();

    for (int kb = 0; kb < niter; ++kb) {
        // prefetch next tile into registers
        uint4 nk0 = {0,0,0,0}, nk1 = {0,0,0,0}, nv0 = {0,0,0,0}, nv1 = {0,0,0,0};
        if (kb < niter - 1) {
            const int keyn = keybase + (kb + 1)*64;
            const uint4* gk = (const uint4*)(Qbase + (size_t)(keyn + lrow)*64 + loff);
            nk0 = gk[0]; nk1 = gk[1];
            const uint4* gv = (const uint4*)(Vbase + (size_t)lrow*4096 + keyn + loff);
            nv0 = gv[0]; nv1 = gv[1];
        }

        // T = K·Qs^T : tt[u] covers keys u*32..+32 (scale pre-folded)
        f32x16 tt[2];
        #pragma unroll
        for (int i = 0; i < 16; ++i) { tt[0][i] = 0.f; tt[1][i] = 0.f; }
        #pragma unroll
        for (int s = 0; s < 4; ++s) {
            const int co = s*16 + hi*8;
            f16x8 ka0 = *(const f16x8*)&Ksh[l32][co];
            f16x8 ka1 = *(const f16x8*)&Ksh[32 + l32][co];
            tt[0] = __builtin_amdgcn_mfma_f32_32x32x16_f16(ka0, qb[s], tt[0], 0,0,0);
            tt[1] = __builtin_amdgcn_mfma_f32_32x32x16_f16(ka1, qb[s], tt[1], 0,0,0);
        }

        // per 32-key tile: sigmoid -> pack -> cross-half swap -> S·V MFMA
        #pragma unroll
        for (int u = 0; u < 2; ++u) {
            float sg[16];
            #pragma unroll
            for (int r = 0; r < 16; ++r) sg[r] = sig_from_t(tt[u][r]);
            #pragma unroll
            for (int ksh = 0; ksh < 2; ++ksh) {
                const int bR = ksh*8;
                unsigned Pa = pkrtz(sg[bR+0], sg[bR+1]);
                unsigned Pb = pkrtz(sg[bR+2], sg[bR+3]);
                unsigned Qa = pkrtz(sg[bR+4], sg[bR+5]);
                unsigned Qb = pkrtz(sg[bR+6], sg[bR+7]);
                unsigned xPa = __shfl_xor(Pa, 32);
                unsigned xPb = __shfl_xor(Pb, 32);
                unsigned xQa = __shfl_xor(Qa, 32);
                unsigned xQb = __shfl_xor(Qb, 32);
                union { unsigned u4[4]; f16x8 v; } sa;
                sa.u4[0] = hi ? xQa : Pa;
                sa.u4[1] = hi ? xQb : Pb;
                sa.u4[2] = hi ? Qa : xPa;
                sa.u4[3] = hi ? Qb : xPb;

                const int ks = u*2 + ksh;           // absolute 16-key step
                const int co = ks*16 + hi*8;
                f16x8 vb0 = *(const f16x8*)&Vts[l32][co];
                f16x8 vb1 = *(const f16x8*)&Vts[32 + l32][co];
                y[0] = __builtin_amdgcn_mfma_f32_32x32x16_f16(sa.v, vb0, y[0], 0,0,0);
                y[1] = __builtin_amdgcn_mfma_f32_32x32x16_f16(sa.v, vb1, y[1], 0,0,0);
            }
        }

        __syncthreads();   // all waves done reading current tile
        if (kb < niter - 1) {
            *(uint4*)&Ksh[lrow][loff]     = nk0;
            *(uint4*)&Ksh[lrow][loff + 8] = nk1;
            *(uint4*)&Vts[lrow][loff]     = nv0;
            *(uint4*)&Vts[lrow][loff + 8] = nv1;
        }
        __syncthreads();   // next tile visible
    }

    // epilogue: P[ksplit][b][d][token]; token = mb*128 + w*32 + 8g + 4hi + e
    float* Pp = P + (((size_t)(ksplit*4 + b)) << 18);
    const int token0 = mb*128 + w*32 + hi*4;
    #pragma unroll
    for (int dt = 0; dt < 2; ++dt) {
        const int d = dt*32 + l32;
        #pragma unroll
        for (int g = 0; g < 4; ++g) {
            float4 v;
            v.x = y[dt][4*g+0]; v.y = y[dt][4*g+1];
            v.z = y[dt][4*g+2]; v.w = y[dt][4*g+3];
            *(float4*)&Pp[(size_t)d*4096 + token0 + 8*g] = v;
        }
    }
}

// ---------------------------------------------------------------------------
// final: out = p * (feature + x1 + g*sum_ks P_w[ks][b][d=w][token=h*64+c])
// ---------------------------------------------------------------------------
__global__ __launch_bounds__(256) void final_kernel(
    const float* __restrict__ feature, const float* __restrict__ x1,
    const float* __restrict__ Pin, const float* __restrict__ predict,
    const float* __restrict__ conv_w, const float* __restrict__ conv_b,
    const float* __restrict__ gate, float* __restrict__ out, int nsplit)
{
    const int i4 = blockIdx.x * 256 + threadIdx.x;   // [0, 262144)
    const int j = i4 << 2;
    const int pix = j >> 6;
    const float* row = predict + (size_t)pix * 19;
    float pv = conv_b[0];
    #pragma unroll
    for (int i = 0; i < 19; ++i) {
        float sg = __builtin_amdgcn_rcpf(1.0f + __builtin_exp2f(-1.442695041f * row[i]));
        pv += (1.0f - sg) * conv_w[i];
    }

    const int b = j >> 18, h = (j >> 12) & 63, d = (j >> 6) & 63, c = j & 63;
    const size_t pif = ((size_t)(b*64 + d) << 12) + h*64 + c;
    float sx = 0.f, sy = 0.f, sz = 0.f, sw = 0.f;
    for (int ks = 0; ks < nsplit; ++ks) {
        float4 pk = *(const float4*)&Pin[((size_t)ks << 20) + pif];
        sx += pk.x; sy += pk.y; sz += pk.z; sw += pk.w;
    }
    const float g = gate[0];
    float4 f = ((const float4*)feature)[i4];
    float4 x = ((const float4*)x1)[i4];
    float4 o;
    o.x = pv * (f.x + x.x + g * sx);
    o.y = pv * (f.y + x.y + g * sy);
    o.z = pv * (f.z + x.z + g * sz);
    o.w = pv * (f.w + x.w + g * sw);
    ((float4*)out)[i4] = o;
}

extern "C" void kernel_launch(void* const* d_in, const int* in_sizes, int n_in,
                              void* d_out, int out_size, void* d_ws, size_t ws_size,
                              hipStream_t stream) {
    const float* feature = (const float*)d_in[0];
    const float* predict = (const float*)d_in[1];
    const float* hq_w = (const float*)d_in[2];
    const float* hq_b = (const float*)d_in[3];
    const float* hv_w = (const float*)d_in[4];
    const float* hv_b = (const float*)d_in[5];
    const float* wq_w = (const float*)d_in[6];
    const float* wq_b = (const float*)d_in[7];
    const float* wv_w = (const float*)d_in[8];
    const float* wv_b = (const float*)d_in[9];
    const float* h_gate = (const float*)d_in[10];
    const float* w_gate = (const float*)d_in[11];
    const float* conv_w = (const float*)d_in[12];
    const float* conv_b = (const float*)d_in[13];
    float* out = (float*)d_out;

    // workspace: Qg 2MB | Vtg 2MB | x1 4MB | P nsplit*4MB (nsplit=4 -> 24 MiB)
    char* ws = (char*)d_ws;
    unsigned short* Qg  = (unsigned short*)(ws);
    unsigned short* Vtg = (unsigned short*)(ws + (2u << 20));
    float*          x1  = (float*)(ws + (4u << 20));
    float*          P   = (float*)(ws + (8u << 20));
    const int nsplit = 4;

    dim3 blk(256);
    // height stage (prep split over z: z=0 Q, z=1 V)
    prep_kernel<<<dim3(64, 4, 2), blk, 0, stream>>>(feature, hq_w, hq_b, hv_w, hv_b,
                                                    Qg, Vtg);
    attn_kernel<<<dim3(32, 4, nsplit), blk, 0, stream>>>(Qg, Vtg, P);
    // width stage: x1 = feature + h_gate*sum(P) fused into staging (z=0 writes x1)
    prep_w_kernel<<<dim3(64, 4, 2), blk, 0, stream>>>(feature, P, h_gate,
                                                      wq_w, wq_b, wv_w, wv_b,
                                                      Qg, Vtg, x1, nsplit);
    attn_kernel<<<dim3(32, 4, nsplit), blk, 0, stream>>>(Qg, Vtg, P);
    // out = p * (feature + x1 + w_gate*sum(P))
    final_kernel<<<dim3(1024), blk, 0, stream>>>(feature, x1, P, predict,
                                                 conv_w, conv_b, w_gate, out, nsplit);
}